// Round 1
// baseline (629.328 us; speedup 1.0000x reference)
//
#include <hip/hip_runtime.h>

#define HH 20
#define WW 20
#define NV 4
#define NKC 12
#define NFC 17
#define TT 96
#define BB 64
#define SIG 306
#define ROW 20   // padded feat row (17 -> 20, keeps 16B alignment for i0 multiples of 4)
#define HALF 48

// ---------------------------------------------------------------------------
// Kernel 1: fused conv + signature (lvl1 + lvl2) + MLP layer 1 (atomic acc)
// grid: 6400 blocks = 64 b * 100 (2x2 pixel tiles), block = 64 threads (1 wave)
// ---------------------------------------------------------------------------
__global__ __launch_bounds__(64) void sig_kernel(
    const float* __restrict__ x,   // (64,96,4,20,20)
    const float* __restrict__ cw,  // (12,4,3,3)
    const float* __restrict__ cb,  // (12,)
    const float* __restrict__ w1,  // (122400,32)
    float* __restrict__ acc)       // (64,32) fp32, pre-zeroed
{
  __shared__ __align__(16) float feat[4 * HALF * ROW + 8];

  const int lane = threadIdx.x;
  const int tile = blockIdx.x;
  const int b  = tile / 100;
  const int tl = tile % 100;
  const int th = (tl / 10) * 2, tw = (tl % 10) * 2;

  // ---- phase-1 mapping: lane = p1*16 + m ----
  const int p1 = lane >> 4;
  const int m  = lane & 15;
  const int h1r = th + (p1 >> 1), w1c = tw + (p1 & 1);

  // branch-free conv prep: clamped offsets + zero-masked weights
  int offc[9];
  float wregm[36];
  float bias = 0.f;
  #pragma unroll
  for (int j = 0; j < 9; j++) offc[j] = 0;
  #pragma unroll
  for (int j = 0; j < 36; j++) wregm[j] = 0.f;
  if (m < NKC) {
    bias = cb[m];
    #pragma unroll
    for (int dy = 0; dy < 3; dy++) {
      #pragma unroll
      for (int dxx = 0; dxx < 3; dxx++) {
        int hh = h1r + dy - 1, ww2 = w1c + dxx - 1;
        bool okk = (hh >= 0 && hh < HH && ww2 >= 0 && ww2 < WW);
        int hc  = min(max(hh, 0), HH - 1);
        int wc2 = min(max(ww2, 0), WW - 1);
        offc[dy * 3 + dxx] = hc * WW + wc2;
        #pragma unroll
        for (int ci = 0; ci < 4; ci++)
          wregm[ci * 9 + dy * 3 + dxx] = okk ? cw[m * 36 + ci * 9 + dy * 3 + dxx] : 0.f;
      }
    }
  }

  // ---- phase-2 mapping: 15 lanes per pixel (5 i-tiles x 3 j-tiles) ----
  const bool active2 = (lane < 60);
  int p2 = 0, it = 0, jt = 0;
  if (active2) { p2 = lane / 15; int r = lane % 15; it = r / 3; jt = r % 3; }
  const int i0 = it * 4, j0 = jt * 8;
  const int h2r = th + (p2 >> 1), w2c = tw + (p2 & 1);

  float accv[4][8];
  #pragma unroll
  for (int i = 0; i < 4; i++)
    #pragma unroll
    for (int j = 0; j < 8; j++) accv[i][j] = 0.f;

  float f0a[4], f0b[8], pa[4], pb[8];
  #pragma unroll
  for (int i = 0; i < 4; i++) { f0a[i] = 0.f; pa[i] = 0.f; }
  #pragma unroll
  for (int j = 0; j < 8; j++) { f0b[j] = 0.f; pb[j] = 0.f; }

  const float inv95 = 1.0f / 95.0f;

  for (int half = 0; half < 2; half++) {
    // ============ phase 1: fill feat[p][tt][c], t = half*48 + tt ============
    for (int tt = 0; tt < HALF; tt++) {
      const int t = half * HALF + tt;
      const float* xb = x + (size_t)(b * TT + t) * (NV * HH * WW);
      float v;
      float* frow = &feat[(p1 * HALF + tt) * ROW];
      if (m < NKC) {
        v = bias;
        #pragma unroll
        for (int ci = 0; ci < 4; ci++) {
          #pragma unroll
          for (int tap = 0; tap < 9; tap++)
            v += xb[ci * 400 + offc[tap]] * wregm[ci * 9 + tap];
        }
        frow[m] = v;
      } else {
        v = xb[(m - 12) * 400 + h1r * WW + w1c];
        frow[m] = v;
        if (m == 12) frow[16] = (float)t * inv95;
        else         frow[m + 4] = 0.f;   // pad channels 17,18,19
      }
    }
    __syncthreads();

    // ============ phase 2: accumulate lvl2 over this half ============
    int tstart;
    if (half == 0) {
      const float* row0 = &feat[(p2 * HALF + 0) * ROW];
      const float4 a4 = *reinterpret_cast<const float4*>(&row0[i0]);
      const float4 b4a = *reinterpret_cast<const float4*>(&row0[j0]);
      const float4 b4b = *reinterpret_cast<const float4*>(&row0[j0 + 4]);
      f0a[0] = a4.x; f0a[1] = a4.y; f0a[2] = a4.z; f0a[3] = a4.w;
      f0b[0] = b4a.x; f0b[1] = b4a.y; f0b[2] = b4a.z; f0b[3] = b4a.w;
      f0b[4] = b4b.x; f0b[5] = b4b.y; f0b[6] = b4b.z; f0b[7] = b4b.w;
      #pragma unroll
      for (int i = 0; i < 4; i++) pa[i] = f0a[i];
      #pragma unroll
      for (int j = 0; j < 8; j++) pb[j] = f0b[j];
      tstart = 1;
    } else {
      tstart = 0;
    }

    for (int tt = tstart; tt < HALF; tt++) {
      const float* row = &feat[(p2 * HALF + tt) * ROW];
      const float4 a4  = *reinterpret_cast<const float4*>(&row[i0]);
      const float4 b4a = *reinterpret_cast<const float4*>(&row[j0]);
      const float4 b4b = *reinterpret_cast<const float4*>(&row[j0 + 4]);
      float fa[4] = {a4.x, a4.y, a4.z, a4.w};
      float fb[8] = {b4a.x, b4a.y, b4a.z, b4a.w, b4b.x, b4b.y, b4b.z, b4b.w};
      float av[4], bv[8];
      #pragma unroll
      for (int i = 0; i < 4; i++) { av[i] = 0.5f * (fa[i] + pa[i]) - f0a[i]; pa[i] = fa[i]; }
      #pragma unroll
      for (int j = 0; j < 8; j++) { bv[j] = fb[j] - pb[j]; pb[j] = fb[j]; }
      #pragma unroll
      for (int i = 0; i < 4; i++)
        #pragma unroll
        for (int j = 0; j < 8; j++) accv[i][j] += av[i] * bv[j];
    }
    __syncthreads();   // protect feat before next half overwrites it
  }

  // ============ fused MLP layer 1 ============
  float mlp[32];
  #pragma unroll
  for (int n = 0; n < 32; n++) mlp[n] = 0.f;

  if (active2) {
    const int pix = h2r * WW + w2c;
    const size_t basef = (size_t)pix * SIG;
    // lvl1 contributions (only jt==0 lanes, avoids triple-count over j-tiles)
    if (jt == 0) {
      #pragma unroll
      for (int ii = 0; ii < 4; ii++) {
        const int i = i0 + ii;
        if (i < NFC) {
          const float sv = pa[ii] - f0a[ii];   // feat[95] - feat[0]
          const float4* wr4 = reinterpret_cast<const float4*>(w1 + (basef + i) * 32);
          #pragma unroll
          for (int q = 0; q < 8; q++) {
            float4 wv = wr4[q];
            mlp[q * 4 + 0] += sv * wv.x; mlp[q * 4 + 1] += sv * wv.y;
            mlp[q * 4 + 2] += sv * wv.z; mlp[q * 4 + 3] += sv * wv.w;
          }
        }
      }
    }
    // lvl2 contributions
    #pragma unroll
    for (int ii = 0; ii < 4; ii++) {
      const int i = i0 + ii;
      if (i < NFC) {
        #pragma unroll
        for (int jj = 0; jj < 8; jj++) {
          const int j = j0 + jj;
          if (j < NFC) {
            const float sv = accv[ii][jj];
            const float4* wr4 = reinterpret_cast<const float4*>(
                w1 + (basef + 17 + (size_t)i * 17 + j) * 32);
            #pragma unroll
            for (int q = 0; q < 8; q++) {
              float4 wv = wr4[q];
              mlp[q * 4 + 0] += sv * wv.x; mlp[q * 4 + 1] += sv * wv.y;
              mlp[q * 4 + 2] += sv * wv.z; mlp[q * 4 + 3] += sv * wv.w;
            }
          }
        }
      }
    }
  }

  // wave-wide reduce (64 lanes) then one atomicAdd per n from lane 0
  #pragma unroll
  for (int n = 0; n < 32; n++) {
    float v = mlp[n];
    #pragma unroll
    for (int o = 32; o >= 1; o >>= 1) v += __shfl_xor(v, o, 64);
    if (lane == 0) atomicAdd(&acc[b * 32 + n], v);
  }
}

// ---------------------------------------------------------------------------
// Kernel 2: MLP layers 2-4. One thread per batch element.
// ---------------------------------------------------------------------------
__global__ __launch_bounds__(64) void mlp_tail(
    const float* __restrict__ acc, const float* __restrict__ b1,
    const float* __restrict__ w2, const float* __restrict__ b2,
    const float* __restrict__ w3, const float* __restrict__ b3,
    const float* __restrict__ w4, const float* __restrict__ b4,
    float* __restrict__ out)
{
  const int b = threadIdx.x;
  float h1v[32], h2v[32];
  #pragma unroll
  for (int n = 0; n < 32; n++) {
    float v = acc[b * 32 + n] + b1[n];
    h1v[n] = v > 0.f ? v : 0.f;
  }
  for (int mm = 0; mm < 32; mm++) {
    float v = b2[mm];
    #pragma unroll
    for (int n = 0; n < 32; n++) v += h1v[n] * w2[n * 32 + mm];
    h2v[mm] = v > 0.f ? v : 0.f;
  }
  for (int mm = 0; mm < 32; mm++) {
    float v = b3[mm];
    #pragma unroll
    for (int n = 0; n < 32; n++) v += h2v[n] * w3[n * 32 + mm];
    h1v[mm] = v > 0.f ? v : 0.f;
  }
  float v = b4[0];
  #pragma unroll
  for (int n = 0; n < 32; n++) v += h1v[n] * w4[n];
  out[b] = v;
}

extern "C" void kernel_launch(void* const* d_in, const int* in_sizes, int n_in,
                              void* d_out, int out_size, void* d_ws, size_t ws_size,
                              hipStream_t stream) {
  const float* x  = (const float*)d_in[0];
  const float* cw = (const float*)d_in[1];
  const float* cb = (const float*)d_in[2];
  const float* w1 = (const float*)d_in[3];
  const float* b1 = (const float*)d_in[4];
  const float* w2 = (const float*)d_in[5];
  const float* b2 = (const float*)d_in[6];
  const float* w3 = (const float*)d_in[7];
  const float* b3 = (const float*)d_in[8];
  const float* w4 = (const float*)d_in[9];
  const float* b4 = (const float*)d_in[10];
  float* out = (float*)d_out;
  float* acc = (float*)d_ws;   // 64*32 fp32 = 8 KB

  hipMemsetAsync(acc, 0, BB * 32 * sizeof(float), stream);
  sig_kernel<<<dim3(6400), dim3(64), 0, stream>>>(x, cw, cb, w1, acc);
  mlp_tail<<<dim3(1), dim3(64), 0, stream>>>(acc, b1, w2, b2, w3, b3, w4, b4, out);
}

// Round 2
// 544.474 us; speedup vs baseline: 1.1558x; 1.1558x over previous
//
#include <hip/hip_runtime.h>

#define HH 20
#define WW 20
#define NV 4
#define NKC 12
#define NFC 17
#define TT 96
#define BB 64
#define SIG 306
#define ROW 20     // padded feat row (17 -> 20, keeps 16B alignment)
#define CHUNK 24   // t-steps per LDS chunk (4 chunks of 24 = 96)
#define NCHUNK 4

// ---------------------------------------------------------------------------
// Kernel 1: fused conv + signature (lvl1 + lvl2) + MLP layer 1 (atomic acc)
// grid: 6400 blocks = 64 b * 100 (2x2 pixel tiles), block = 64 threads (1 wave)
// x is staged through LDS (double-buffered, 1 coalesced wave-load per t).
// ---------------------------------------------------------------------------
__global__ __launch_bounds__(64) void sig_kernel(
    const float* __restrict__ x,   // (64,96,4,20,20)
    const float* __restrict__ cw,  // (12,4,3,3)
    const float* __restrict__ cb,  // (12,)
    const float* __restrict__ w1,  // (122400,32)
    float* __restrict__ acc)       // (64,32) fp32, pre-zeroed
{
  __shared__ __align__(16) float feat[4 * CHUNK * ROW + 8];
  __shared__ float xs[2][64];

  const int lane = threadIdx.x;
  const int tile = blockIdx.x;
  const int b  = tile / 100;
  const int tl = tile % 100;
  const int th = (tl / 10) * 2, tw = (tl % 10) * 2;

  // ---- x staging map: lane = ci*16 + (row*4 + col) of the 4x4 halo ----
  const int sci  = lane >> 4;
  const int spos = lane & 15;
  const int srow = spos >> 2, scol = spos & 3;
  const int xr = min(max(th - 1 + srow, 0), HH - 1);
  const int xc = min(max(tw - 1 + scol, 0), WW - 1);
  const int off_stage = sci * 400 + xr * WW + xc;
  const float* xb0 = x + (size_t)b * TT * (NV * HH * WW);

  // ---- phase-1 mapping: lane = p1*16 + m ----
  const int p1 = lane >> 4;
  const int m  = lane & 15;
  const int p1y = p1 >> 1, p1x = p1 & 1;
  const int h1r = th + p1y, w1c = tw + p1x;
  const int cidx = (p1y + 1) * 4 + (p1x + 1);   // center of 4x4 halo window

  // conv prep: LDS-window tap indices + zero-masked weights (handles borders)
  int lidx[9];
  float wregm[36];
  float bias = 0.f;
  #pragma unroll
  for (int j = 0; j < 9; j++) lidx[j] = 0;
  #pragma unroll
  for (int j = 0; j < 36; j++) wregm[j] = 0.f;
  if (m < NKC) {
    bias = cb[m];
    #pragma unroll
    for (int dy = 0; dy < 3; dy++) {
      #pragma unroll
      for (int dxx = 0; dxx < 3; dxx++) {
        int hh = h1r + dy - 1, ww2 = w1c + dxx - 1;
        bool okk = (hh >= 0 && hh < HH && ww2 >= 0 && ww2 < WW);
        lidx[dy * 3 + dxx] = (p1y + dy) * 4 + (p1x + dxx);
        #pragma unroll
        for (int ci = 0; ci < 4; ci++)
          wregm[ci * 9 + dy * 3 + dxx] = okk ? cw[m * 36 + ci * 9 + dy * 3 + dxx] : 0.f;
      }
    }
  }

  // ---- phase-2 mapping: 15 lanes per pixel (5 i-tiles x 3 j-tiles) ----
  const bool active2 = (lane < 60);
  int p2 = 0, it = 0, jt = 0;
  if (active2) { p2 = lane / 15; int r = lane % 15; it = r / 3; jt = r % 3; }
  const int i0 = it * 4, j0 = jt * 8;
  const int h2r = th + (p2 >> 1), w2c = tw + (p2 & 1);

  float accv[4][8];
  #pragma unroll
  for (int i = 0; i < 4; i++)
    #pragma unroll
    for (int j = 0; j < 8; j++) accv[i][j] = 0.f;

  float f0a[4], f0b[8], pa[4], pb[8];
  #pragma unroll
  for (int i = 0; i < 4; i++) { f0a[i] = 0.f; pa[i] = 0.f; }
  #pragma unroll
  for (int j = 0; j < 8; j++) { f0b[j] = 0.f; pb[j] = 0.f; }

  const float inv95 = 1.0f / 95.0f;

  int buf = 0;
  xs[0][lane] = xb0[off_stage];   // stage t = 0

  for (int chunk = 0; chunk < NCHUNK; chunk++) {
    // ============ phase 1: fill feat[p][tt][c] for this chunk ============
    for (int tt = 0; tt < CHUNK; tt++) {
      const int t = chunk * CHUNK + tt;
      __syncthreads();   // xs[buf] visible; prev reads drained
      if (t + 1 < TT)
        xs[buf ^ 1][lane] = xb0[(size_t)(t + 1) * (NV * HH * WW) + off_stage];
      const float* xcur = xs[buf];
      float* frow = &feat[(p1 * CHUNK + tt) * ROW];
      if (m < NKC) {
        float v = bias;
        #pragma unroll
        for (int ci = 0; ci < 4; ci++) {
          #pragma unroll
          for (int tap = 0; tap < 9; tap++)
            v += xcur[ci * 16 + lidx[tap]] * wregm[ci * 9 + tap];
        }
        frow[m] = v;
      } else {
        frow[m] = xcur[(m - 12) * 16 + cidx];
        if (m == 12) frow[16] = (float)t * inv95;
        else         frow[m + 4] = 0.f;   // pad channels 17,18,19
      }
      buf ^= 1;
    }
    __syncthreads();   // feat complete for this chunk

    // ============ phase 2: accumulate lvl2 over this chunk ============
    int tstart;
    if (chunk == 0) {
      const float* row0 = &feat[(p2 * CHUNK + 0) * ROW];
      const float4 a4  = *reinterpret_cast<const float4*>(&row0[i0]);
      const float4 b4a = *reinterpret_cast<const float4*>(&row0[j0]);
      const float4 b4b = *reinterpret_cast<const float4*>(&row0[j0 + 4]);
      f0a[0] = a4.x; f0a[1] = a4.y; f0a[2] = a4.z; f0a[3] = a4.w;
      f0b[0] = b4a.x; f0b[1] = b4a.y; f0b[2] = b4a.z; f0b[3] = b4a.w;
      f0b[4] = b4b.x; f0b[5] = b4b.y; f0b[6] = b4b.z; f0b[7] = b4b.w;
      #pragma unroll
      for (int i = 0; i < 4; i++) pa[i] = f0a[i];
      #pragma unroll
      for (int j = 0; j < 8; j++) pb[j] = f0b[j];
      tstart = 1;
    } else {
      tstart = 0;
    }

    for (int tt = tstart; tt < CHUNK; tt++) {
      const float* row = &feat[(p2 * CHUNK + tt) * ROW];
      const float4 a4  = *reinterpret_cast<const float4*>(&row[i0]);
      const float4 b4a = *reinterpret_cast<const float4*>(&row[j0]);
      const float4 b4b = *reinterpret_cast<const float4*>(&row[j0 + 4]);
      float fa[4] = {a4.x, a4.y, a4.z, a4.w};
      float fb[8] = {b4a.x, b4a.y, b4a.z, b4a.w, b4b.x, b4b.y, b4b.z, b4b.w};
      float av[4], bv[8];
      #pragma unroll
      for (int i = 0; i < 4; i++) { av[i] = 0.5f * (fa[i] + pa[i]) - f0a[i]; pa[i] = fa[i]; }
      #pragma unroll
      for (int j = 0; j < 8; j++) { bv[j] = fb[j] - pb[j]; pb[j] = fb[j]; }
      #pragma unroll
      for (int i = 0; i < 4; i++)
        #pragma unroll
        for (int j = 0; j < 8; j++) accv[i][j] += av[i] * bv[j];
    }
    __syncthreads();   // protect feat before next chunk overwrites it
  }

  // ============ fused MLP layer 1 ============
  float mlp[32];
  #pragma unroll
  for (int n = 0; n < 32; n++) mlp[n] = 0.f;

  if (active2) {
    const int pix = h2r * WW + w2c;
    const size_t basef = (size_t)pix * SIG;
    // lvl1 contributions (only jt==0 lanes, avoids triple-count over j-tiles)
    if (jt == 0) {
      #pragma unroll
      for (int ii = 0; ii < 4; ii++) {
        const int i = i0 + ii;
        if (i < NFC) {
          const float sv = pa[ii] - f0a[ii];   // feat[95] - feat[0]
          const float4* wr4 = reinterpret_cast<const float4*>(w1 + (basef + i) * 32);
          #pragma unroll
          for (int q = 0; q < 8; q++) {
            float4 wv = wr4[q];
            mlp[q * 4 + 0] += sv * wv.x; mlp[q * 4 + 1] += sv * wv.y;
            mlp[q * 4 + 2] += sv * wv.z; mlp[q * 4 + 3] += sv * wv.w;
          }
        }
      }
    }
    // lvl2 contributions
    #pragma unroll
    for (int ii = 0; ii < 4; ii++) {
      const int i = i0 + ii;
      if (i < NFC) {
        #pragma unroll
        for (int jj = 0; jj < 8; jj++) {
          const int j = j0 + jj;
          if (j < NFC) {
            const float sv = accv[ii][jj];
            const float4* wr4 = reinterpret_cast<const float4*>(
                w1 + (basef + 17 + (size_t)i * 17 + j) * 32);
            #pragma unroll
            for (int q = 0; q < 8; q++) {
              float4 wv = wr4[q];
              mlp[q * 4 + 0] += sv * wv.x; mlp[q * 4 + 1] += sv * wv.y;
              mlp[q * 4 + 2] += sv * wv.z; mlp[q * 4 + 3] += sv * wv.w;
            }
          }
        }
      }
    }
  }

  // wave-wide reduce (64 lanes) then one atomicAdd per n from lane 0
  #pragma unroll
  for (int n = 0; n < 32; n++) {
    float v = mlp[n];
    #pragma unroll
    for (int o = 32; o >= 1; o >>= 1) v += __shfl_xor(v, o, 64);
    if (lane == 0) atomicAdd(&acc[b * 32 + n], v);
  }
}

// ---------------------------------------------------------------------------
// Kernel 2: MLP layers 2-4. One thread per batch element.
// ---------------------------------------------------------------------------
__global__ __launch_bounds__(64) void mlp_tail(
    const float* __restrict__ acc, const float* __restrict__ b1,
    const float* __restrict__ w2, const float* __restrict__ b2,
    const float* __restrict__ w3, const float* __restrict__ b3,
    const float* __restrict__ w4, const float* __restrict__ b4,
    float* __restrict__ out)
{
  const int b = threadIdx.x;
  float h1v[32], h2v[32];
  #pragma unroll
  for (int n = 0; n < 32; n++) {
    float v = acc[b * 32 + n] + b1[n];
    h1v[n] = v > 0.f ? v : 0.f;
  }
  for (int mm = 0; mm < 32; mm++) {
    float v = b2[mm];
    #pragma unroll
    for (int n = 0; n < 32; n++) v += h1v[n] * w2[n * 32 + mm];
    h2v[mm] = v > 0.f ? v : 0.f;
  }
  for (int mm = 0; mm < 32; mm++) {
    float v = b3[mm];
    #pragma unroll
    for (int n = 0; n < 32; n++) v += h2v[n] * w3[n * 32 + mm];
    h1v[mm] = v > 0.f ? v : 0.f;
  }
  float v = b4[0];
  #pragma unroll
  for (int n = 0; n < 32; n++) v += h1v[n] * w4[n];
  out[b] = v;
}

extern "C" void kernel_launch(void* const* d_in, const int* in_sizes, int n_in,
                              void* d_out, int out_size, void* d_ws, size_t ws_size,
                              hipStream_t stream) {
  const float* x  = (const float*)d_in[0];
  const float* cw = (const float*)d_in[1];
  const float* cb = (const float*)d_in[2];
  const float* w1 = (const float*)d_in[3];
  const float* b1 = (const float*)d_in[4];
  const float* w2 = (const float*)d_in[5];
  const float* b2 = (const float*)d_in[6];
  const float* w3 = (const float*)d_in[7];
  const float* b3 = (const float*)d_in[8];
  const float* w4 = (const float*)d_in[9];
  const float* b4 = (const float*)d_in[10];
  float* out = (float*)d_out;
  float* acc = (float*)d_ws;   // 64*32 fp32 = 8 KB

  hipMemsetAsync(acc, 0, BB * 32 * sizeof(float), stream);
  sig_kernel<<<dim3(6400), dim3(64), 0, stream>>>(x, cw, cb, w1, acc);
  mlp_tail<<<dim3(1), dim3(64), 0, stream>>>(acc, b1, w2, b2, w3, b3, w4, b4, out);
}

// Round 3
// 308.884 us; speedup vs baseline: 2.0374x; 1.7627x over previous
//
#include <hip/hip_runtime.h>

#define HH 20
#define WW 20
#define TT 96
#define BB 64
#define SIG 306
#define NFC 17
#define ROW 20      // feat row: 12 conv + 4 x + tch + 3 pad (5 x float4)
#define CHUNK 16    // t-steps per chunk; 64 lanes = 4 pixels x 16 t exactly
#define NCHUNK 6
#define XS_ROW 65   // x-stage row pad (65 odd -> conflict-free strided reads)
#define KTOT 122400 // 400 pixels * 306 sig
#define KS 120      // GEMM K-slab (122400 = 1020 * 120)
#define NKBLK 1020

// ---------------------------------------------------------------------------
// Kernel 1: conv + signature. One wave (64 thr) per (b, 2x2 pixel tile).
// Phase 1: lane = (pixel, t) computes all 12 conv ch + passthrough from a
//          register window; weights broadcast from LDS (ds_read_b128).
// Phase 2: lane = (pixel, i-tile, j-tile) accumulates lvl2 outer products.
// Tail: WRITE_SIG ? store sig to workspace : fused MLP-1 (fallback).
// ---------------------------------------------------------------------------
template<bool WRITE_SIG>
__global__ __launch_bounds__(64) void sig_kernel(
    const float* __restrict__ x,   // (64,96,4,20,20)
    const float* __restrict__ cw,  // (12,4,3,3)
    const float* __restrict__ cb,  // (12,)
    const float* __restrict__ w1,  // (122400,32) [fused path only]
    float* __restrict__ acc,       // (64,32) zeroed [fused path only]
    float* __restrict__ sig)       // (64,122400) [WRITE_SIG path only]
{
  __shared__ __align__(16) float feat[4 * CHUNK * ROW + 8];
  __shared__ __align__(16) float xs[CHUNK * XS_ROW];
  __shared__ __align__(16) float wlds[12 * 48];   // [k][ci][dy][4] dx-padded
  __shared__ float wb[12];

  const int lane = threadIdx.x;
  const int tile = blockIdx.x;
  const int b  = tile / 100;
  const int tl = tile % 100;
  const int th = (tl / 10) * 2, tw = (tl % 10) * 2;

  // ---- stage weights to LDS (padded for aligned b128 broadcast) ----
  #pragma unroll
  for (int r = 0; r < 9; r++) {
    int idx = r * 64 + lane;               // 576 = 9*64
    int k = idx / 48, rem = idx % 48;
    int ci = rem / 12, r2 = rem % 12, dy = r2 >> 2, dx = r2 & 3;
    wlds[idx] = (dx < 3) ? cw[k * 36 + ci * 9 + dy * 3 + dx] : 0.f;
  }
  if (lane < 12) wb[lane] = cb[lane];

  // ---- x staging map: lane = ci*16 + (srow*4 + scol) of 4x4 halo ----
  const int sci  = lane >> 4;
  const int spos = lane & 15;
  const int srow = spos >> 2, scol = spos & 3;
  const int gr = th - 1 + srow, gc = tw - 1 + scol;
  const bool okst = (gr >= 0 && gr < HH && gc >= 0 && gc < WW);
  const int xoff = sci * 400 + (okst ? gr * WW + gc : 0);
  const float* xb0 = x + (size_t)b * TT * 1600;

  // ---- conv map: lane = pixel*16 + tt ----
  const int cp  = lane >> 4;
  const int ctt = lane & 15;
  const int cpy = cp >> 1, cpx = cp & 1;

  // ---- phase-2 map: 15 lanes per pixel (5 i-tiles x 3 j-tiles) ----
  const bool active2 = (lane < 60);
  int p2 = 0, it = 0, jt = 0;
  if (active2) { p2 = lane / 15; int r = lane % 15; it = r / 3; jt = r % 3; }
  const int i0 = it * 4, j0 = jt * 8;
  const int h2r = th + (p2 >> 1), w2c = tw + (p2 & 1);

  float accv[4][8];
  #pragma unroll
  for (int i = 0; i < 4; i++)
    #pragma unroll
    for (int j = 0; j < 8; j++) accv[i][j] = 0.f;

  float f0a[4], f0b[8], pa[4], pb[8];
  #pragma unroll
  for (int i = 0; i < 4; i++) { f0a[i] = 0.f; pa[i] = 0.f; }
  #pragma unroll
  for (int j = 0; j < 8; j++) { f0b[j] = 0.f; pb[j] = 0.f; }

  const float inv95 = 1.0f / 95.0f;

  __syncthreads();   // weights staged
  float breg[12];
  #pragma unroll
  for (int k = 0; k < 12; k++) breg[k] = wb[k];

  for (int chunk = 0; chunk < NCHUNK; chunk++) {
    // ===== stage this chunk's x: 16 loads in flight, then LDS writes =====
    {
      float rg[CHUNK];
      const float* xb = xb0 + (size_t)chunk * CHUNK * 1600 + xoff;
      #pragma unroll
      for (int i = 0; i < CHUNK; i++)
        rg[i] = okst ? xb[i * 1600] : 0.f;   // OOB halo = 0 (SAME padding)
      #pragma unroll
      for (int i = 0; i < CHUNK; i++)
        xs[i * XS_ROW + lane] = rg[i];
    }
    __syncthreads();

    // ===== conv: this lane's (pixel, t) full feat row =====
    {
      float win[4][9];
      #pragma unroll
      for (int ci = 0; ci < 4; ci++)
        #pragma unroll
        for (int dy = 0; dy < 3; dy++)
          #pragma unroll
          for (int dxx = 0; dxx < 3; dxx++)
            win[ci][dy * 3 + dxx] =
                xs[ctt * XS_ROW + ci * 16 + (cpy + dy) * 4 + (cpx + dxx)];

      float fk[12];
      #pragma unroll
      for (int k = 0; k < 12; k++) {
        float a = breg[k];
        #pragma unroll
        for (int ci = 0; ci < 4; ci++) {
          #pragma unroll
          for (int dy = 0; dy < 3; dy++) {
            const float4 w4 = *reinterpret_cast<const float4*>(
                &wlds[k * 48 + ci * 12 + dy * 4]);
            a += win[ci][dy * 3 + 0] * w4.x + win[ci][dy * 3 + 1] * w4.y +
                 win[ci][dy * 3 + 2] * w4.z;
          }
        }
        fk[k] = a;
      }
      // feat row index = cp*CHUNK + ctt = lane
      float* fr = &feat[lane * ROW];
      *reinterpret_cast<float4*>(fr + 0)  = make_float4(fk[0], fk[1], fk[2], fk[3]);
      *reinterpret_cast<float4*>(fr + 4)  = make_float4(fk[4], fk[5], fk[6], fk[7]);
      *reinterpret_cast<float4*>(fr + 8)  = make_float4(fk[8], fk[9], fk[10], fk[11]);
      *reinterpret_cast<float4*>(fr + 12) = make_float4(win[0][4], win[1][4], win[2][4], win[3][4]);
      const float tch = (float)(chunk * CHUNK + ctt) * inv95;
      *reinterpret_cast<float4*>(fr + 16) = make_float4(tch, 0.f, 0.f, 0.f);
    }
    __syncthreads();

    // ===== phase 2: accumulate lvl2 over this chunk =====
    int tstart;
    if (chunk == 0) {
      const float* row0 = &feat[(p2 * CHUNK + 0) * ROW];
      const float4 a4  = *reinterpret_cast<const float4*>(&row0[i0]);
      const float4 b4a = *reinterpret_cast<const float4*>(&row0[j0]);
      const float4 b4b = *reinterpret_cast<const float4*>(&row0[j0 + 4]);
      f0a[0] = a4.x; f0a[1] = a4.y; f0a[2] = a4.z; f0a[3] = a4.w;
      f0b[0] = b4a.x; f0b[1] = b4a.y; f0b[2] = b4a.z; f0b[3] = b4a.w;
      f0b[4] = b4b.x; f0b[5] = b4b.y; f0b[6] = b4b.z; f0b[7] = b4b.w;
      #pragma unroll
      for (int i = 0; i < 4; i++) pa[i] = f0a[i];
      #pragma unroll
      for (int j = 0; j < 8; j++) pb[j] = f0b[j];
      tstart = 1;
    } else {
      tstart = 0;
    }

    for (int tt = tstart; tt < CHUNK; tt++) {
      const float* row = &feat[(p2 * CHUNK + tt) * ROW];
      const float4 a4  = *reinterpret_cast<const float4*>(&row[i0]);
      const float4 b4a = *reinterpret_cast<const float4*>(&row[j0]);
      const float4 b4b = *reinterpret_cast<const float4*>(&row[j0 + 4]);
      float fa[4] = {a4.x, a4.y, a4.z, a4.w};
      float fb[8] = {b4a.x, b4a.y, b4a.z, b4a.w, b4b.x, b4b.y, b4b.z, b4b.w};
      float av[4], bv[8];
      #pragma unroll
      for (int i = 0; i < 4; i++) { av[i] = 0.5f * (fa[i] + pa[i]) - f0a[i]; pa[i] = fa[i]; }
      #pragma unroll
      for (int j = 0; j < 8; j++) { bv[j] = fb[j] - pb[j]; pb[j] = fb[j]; }
      #pragma unroll
      for (int i = 0; i < 4; i++)
        #pragma unroll
        for (int j = 0; j < 8; j++) accv[i][j] += av[i] * bv[j];
    }
    __syncthreads();
  }

  // ======================= tail =======================
  if (WRITE_SIG) {
    if (active2) {
      float* sb = sig + (size_t)b * KTOT + (size_t)(h2r * WW + w2c) * SIG;
      if (jt == 0) {
        #pragma unroll
        for (int ii = 0; ii < 4; ii++) {
          const int i = i0 + ii;
          if (i < NFC) sb[i] = pa[ii] - f0a[ii];   // lvl1 = feat[95]-feat[0]
        }
      }
      #pragma unroll
      for (int ii = 0; ii < 4; ii++) {
        const int i = i0 + ii;
        if (i < NFC) {
          #pragma unroll
          for (int jj = 0; jj < 8; jj++) {
            const int j = j0 + jj;
            if (j < NFC) sb[NFC + i * NFC + j] = accv[ii][jj];
          }
        }
      }
    }
  } else {
    // fused MLP layer 1 (fallback when workspace too small)
    float mlp[32];
    #pragma unroll
    for (int n = 0; n < 32; n++) mlp[n] = 0.f;
    if (active2) {
      const size_t basef = (size_t)(h2r * WW + w2c) * SIG;
      if (jt == 0) {
        #pragma unroll
        for (int ii = 0; ii < 4; ii++) {
          const int i = i0 + ii;
          if (i < NFC) {
            const float sv = pa[ii] - f0a[ii];
            const float4* wr4 = reinterpret_cast<const float4*>(w1 + (basef + i) * 32);
            #pragma unroll
            for (int q = 0; q < 8; q++) {
              float4 wv = wr4[q];
              mlp[q * 4 + 0] += sv * wv.x; mlp[q * 4 + 1] += sv * wv.y;
              mlp[q * 4 + 2] += sv * wv.z; mlp[q * 4 + 3] += sv * wv.w;
            }
          }
        }
      }
      #pragma unroll
      for (int ii = 0; ii < 4; ii++) {
        const int i = i0 + ii;
        if (i < NFC) {
          #pragma unroll
          for (int jj = 0; jj < 8; jj++) {
            const int j = j0 + jj;
            if (j < NFC) {
              const float sv = accv[ii][jj];
              const float4* wr4 = reinterpret_cast<const float4*>(
                  w1 + (basef + NFC + (size_t)i * NFC + j) * 32);
              #pragma unroll
              for (int q = 0; q < 8; q++) {
                float4 wv = wr4[q];
                mlp[q * 4 + 0] += sv * wv.x; mlp[q * 4 + 1] += sv * wv.y;
                mlp[q * 4 + 2] += sv * wv.z; mlp[q * 4 + 3] += sv * wv.w;
              }
            }
          }
        }
      }
    }
    #pragma unroll
    for (int n = 0; n < 32; n++) {
      float v = mlp[n];
      #pragma unroll
      for (int o = 32; o >= 1; o >>= 1) v += __shfl_xor(v, o, 64);
      if (lane == 0) atomicAdd(&acc[b * 32 + n], v);
    }
  }
}

// ---------------------------------------------------------------------------
// Kernel 2: MLP-1 as K-split GEMM. acc(64,32) += sig(64,122400) @ w1(122400,32)
// Each block handles a K-slab of 120; w1 is read exactly once device-wide.
// ---------------------------------------------------------------------------
__global__ __launch_bounds__(256) void mlp1_gemm(
    const float* __restrict__ sig, const float* __restrict__ w1,
    float* __restrict__ acc)
{
  __shared__ __align__(16) float ldsT[KS * 68];   // [k][b], row pad 68
  const int tid = threadIdx.x;
  const int k0 = blockIdx.x * KS;

  #pragma unroll
  for (int r = 0; r < (64 * KS) / 256; r++) {   // 30
    int idx = r * 256 + tid;
    int b = idx / KS, kk = idx % KS;
    ldsT[kk * 68 + b] = sig[(size_t)b * KTOT + k0 + kk];
  }
  __syncthreads();

  const int n = tid & 31, bq = tid >> 5;
  float a8[8];
  #pragma unroll
  for (int i = 0; i < 8; i++) a8[i] = 0.f;
  const float* w1p = w1 + (size_t)k0 * 32 + n;

  #pragma unroll 4
  for (int kk = 0; kk < KS; kk++) {
    const float w = w1p[(size_t)kk * 32];
    const float4 s0 = *reinterpret_cast<const float4*>(&ldsT[kk * 68 + bq * 8]);
    const float4 s1 = *reinterpret_cast<const float4*>(&ldsT[kk * 68 + bq * 8 + 4]);
    a8[0] += s0.x * w; a8[1] += s0.y * w; a8[2] += s0.z * w; a8[3] += s0.w * w;
    a8[4] += s1.x * w; a8[5] += s1.y * w; a8[6] += s1.z * w; a8[7] += s1.w * w;
  }
  #pragma unroll
  for (int i = 0; i < 8; i++)
    atomicAdd(&acc[(bq * 8 + i) * 32 + n], a8[i]);
}

// ---------------------------------------------------------------------------
// Kernel 3: MLP layers 2-4. One thread per batch element.
// ---------------------------------------------------------------------------
__global__ __launch_bounds__(64) void mlp_tail(
    const float* __restrict__ acc, const float* __restrict__ b1,
    const float* __restrict__ w2, const float* __restrict__ b2,
    const float* __restrict__ w3, const float* __restrict__ b3,
    const float* __restrict__ w4, const float* __restrict__ b4,
    float* __restrict__ out)
{
  const int b = threadIdx.x;
  float h1v[32], h2v[32];
  #pragma unroll
  for (int n = 0; n < 32; n++) {
    float v = acc[b * 32 + n] + b1[n];
    h1v[n] = v > 0.f ? v : 0.f;
  }
  for (int mm = 0; mm < 32; mm++) {
    float v = b2[mm];
    #pragma unroll
    for (int n = 0; n < 32; n++) v += h1v[n] * w2[n * 32 + mm];
    h2v[mm] = v > 0.f ? v : 0.f;
  }
  for (int mm = 0; mm < 32; mm++) {
    float v = b3[mm];
    #pragma unroll
    for (int n = 0; n < 32; n++) v += h2v[n] * w3[n * 32 + mm];
    h1v[mm] = v > 0.f ? v : 0.f;
  }
  float v = b4[0];
  #pragma unroll
  for (int n = 0; n < 32; n++) v += h1v[n] * w4[n];
  out[b] = v;
}

extern "C" void kernel_launch(void* const* d_in, const int* in_sizes, int n_in,
                              void* d_out, int out_size, void* d_ws, size_t ws_size,
                              hipStream_t stream) {
  const float* x  = (const float*)d_in[0];
  const float* cw = (const float*)d_in[1];
  const float* cb = (const float*)d_in[2];
  const float* w1 = (const float*)d_in[3];
  const float* b1 = (const float*)d_in[4];
  const float* w2 = (const float*)d_in[5];
  const float* b2 = (const float*)d_in[6];
  const float* w3 = (const float*)d_in[7];
  const float* b3 = (const float*)d_in[8];
  const float* w4 = (const float*)d_in[9];
  const float* b4 = (const float*)d_in[10];
  float* out = (float*)d_out;

  float* acc  = (float*)d_ws;                       // 8 KB
  float* sigm = (float*)((char*)d_ws + 8192);       // 31.3 MB
  const size_t need = (size_t)8192 + (size_t)BB * KTOT * sizeof(float);
  const bool use_ws = ws_size >= need;

  hipMemsetAsync(acc, 0, BB * 32 * sizeof(float), stream);
  if (use_ws) {
    sig_kernel<true><<<dim3(6400), dim3(64), 0, stream>>>(x, cw, cb, w1, acc, sigm);
    mlp1_gemm<<<dim3(NKBLK), dim3(256), 0, stream>>>(sigm, w1, acc);
  } else {
    sig_kernel<false><<<dim3(6400), dim3(64), 0, stream>>>(x, cw, cb, w1, acc, nullptr);
  }
  mlp_tail<<<dim3(1), dim3(64), 0, stream>>>(acc, b1, w2, b2, w3, b3, w4, b4, out);
}

// Round 4
// 282.500 us; speedup vs baseline: 2.2277x; 1.0934x over previous
//
#include <hip/hip_runtime.h>

#define HH 20
#define WW 20
#define TT 96
#define BB 64
#define SIG 306
#define NFC 17
#define FROW 16        // feat channels stored (12 conv + 4 raw); tch is analytic
#define PIXSTRIDE 260  // 16*16+4 floats per pixel in feat LDS (de-alias banks)
#define CHUNK 16
#define NCHUNK 6
#define XT 193         // xs per-t stride (4ci*48=192 +1, odd -> bank spread)
#define KTOT 122400
#define KS 120
#define NKBLK 1020

// ---------------------------------------------------------------------------
// Kernel 1: conv + signature -> sig workspace.
// Block = 256 thr (4 waves) = one (b, 4x4-pixel tile). Grid 64*25 = 1600.
//   stage:  6x6 halo x 4ch x 16t staged to LDS (9 loads/thread, zero-filled OOB)
//   conv:   lane=(pix,tt) computes 12 conv ch + 4 raw -> feat[pix][tt][16]
//   phase2: lane=(pix,it,jt) 4x4 tile of the 16x16 lvl2 core; tch row/col/corner
//           reconstructed analytically from fsum,f0,f95 at the end.
// ---------------------------------------------------------------------------
__global__ __launch_bounds__(256) void sig_kernel(
    const float* __restrict__ x,   // (64,96,4,20,20)
    const float* __restrict__ cw,  // (12,4,3,3)
    const float* __restrict__ cb,  // (12,)
    float* __restrict__ sig)       // (64,122400)
{
  __shared__ __align__(16) float feat[16 * PIXSTRIDE];
  __shared__ __align__(16) float xs[CHUNK * XT];
  __shared__ __align__(16) float wlds[12 * 48];   // [k][ci][dy][4], dx pad=0
  __shared__ float wb[12];

  const int tid = threadIdx.x;
  const int blk = blockIdx.x;
  const int b = blk / 25;
  const int tile = blk % 25;
  const int th4 = (tile / 5) * 4, tw4 = (tile % 5) * 4;
  const float* xb0 = x + (size_t)b * TT * 1600;

  // ---- stage conv weights (once) ----
  #pragma unroll
  for (int r = 0; r < 3; r++) {
    int idx = r * 256 + tid;
    if (idx < 576) {
      int k = idx / 48, rem = idx % 48;
      int ci = rem / 12, r2 = rem % 12, dy = r2 >> 2, dx = r2 & 3;
      wlds[idx] = (dx < 3) ? cw[k * 36 + ci * 9 + dy * 3 + dx] : 0.f;
    }
  }
  if (tid < 12) wb[tid] = cb[tid];

  // ---- staging precompute: 2304 = 9*256 halo values per chunk ----
  int g_off[9], l_off[9];
  bool valid[9];
  #pragma unroll
  for (int r = 0; r < 9; r++) {
    int idx = r * 256 + tid;                 // < 2304
    int t = idx / 144, q = idx % 144;
    int ci = q / 36, pos = q % 36, row = pos / 6, col = pos % 6;
    int gr = th4 - 1 + row, gc = tw4 - 1 + col;
    valid[r] = (gr >= 0 && gr < HH && gc >= 0 && gc < WW);
    g_off[r] = t * 1600 + ci * 400 + (valid[r] ? gr * WW + gc : 0);
    l_off[r] = t * XT + ci * 48 + row * 8 + col;
  }

  // ---- conv mapping: lane = pix*16 + tt ----
  const int cpix = tid >> 4, ctt = tid & 15;
  const int cpy = cpix >> 2, cpx = cpix & 3;

  // ---- phase-2 mapping: lane = pix*16 + (it*4 + jt) ----
  const int p2 = tid >> 4;
  const int rr = tid & 15, it = rr >> 2, jt = rr & 3;
  const int i0 = it * 4, j0 = jt * 4;

  float accv[4][4];
  float f0a[4], f0b[4], pa[4], pb[4], fsum[4];
  #pragma unroll
  for (int i = 0; i < 4; i++) {
    f0a[i] = 0.f; f0b[i] = 0.f; pa[i] = 0.f; pb[i] = 0.f; fsum[i] = 0.f;
    #pragma unroll
    for (int j = 0; j < 4; j++) accv[i][j] = 0.f;
  }

  __syncthreads();   // weights staged
  float breg[12];
  #pragma unroll
  for (int k = 0; k < 12; k++) breg[k] = wb[k];

  for (int chunk = 0; chunk < NCHUNK; chunk++) {
    // ===== stage x halo for this chunk =====
    {
      const float* xbc = xb0 + (size_t)chunk * CHUNK * 1600;
      float rg[9];
      #pragma unroll
      for (int r = 0; r < 9; r++)
        rg[r] = valid[r] ? xbc[g_off[r]] : 0.f;
      #pragma unroll
      for (int r = 0; r < 9; r++) xs[l_off[r]] = rg[r];
    }
    __syncthreads();   // xs ready (also: prev phase-2 done before feat rewrite)

    // ===== conv: this lane's (pixel, t) 16-channel feat row =====
    {
      float win[4][9];
      const int wb2 = ctt * XT;
      #pragma unroll
      for (int ci = 0; ci < 4; ci++)
        #pragma unroll
        for (int dy = 0; dy < 3; dy++)
          #pragma unroll
          for (int dxx = 0; dxx < 3; dxx++)
            win[ci][dy * 3 + dxx] = xs[wb2 + ci * 48 + (cpy + dy) * 8 + (cpx + dxx)];

      float fk[12];
      #pragma unroll
      for (int k = 0; k < 12; k++) {
        float a = breg[k];
        #pragma unroll
        for (int ci = 0; ci < 4; ci++) {
          #pragma unroll
          for (int dy = 0; dy < 3; dy++) {
            const float4 w4 = *reinterpret_cast<const float4*>(
                &wlds[k * 48 + ci * 12 + dy * 4]);
            a += win[ci][dy * 3 + 0] * w4.x + win[ci][dy * 3 + 1] * w4.y +
                 win[ci][dy * 3 + 2] * w4.z;
          }
        }
        fk[k] = a;
      }
      float* fr = &feat[cpix * PIXSTRIDE + ctt * FROW];
      *reinterpret_cast<float4*>(fr + 0)  = make_float4(fk[0], fk[1], fk[2], fk[3]);
      *reinterpret_cast<float4*>(fr + 4)  = make_float4(fk[4], fk[5], fk[6], fk[7]);
      *reinterpret_cast<float4*>(fr + 8)  = make_float4(fk[8], fk[9], fk[10], fk[11]);
      *reinterpret_cast<float4*>(fr + 12) = make_float4(win[0][4], win[1][4], win[2][4], win[3][4]);
    }
    __syncthreads();   // feat ready

    // ===== phase 2: 4x4 tile of the 16x16 lvl2 core =====
    int tstart = 0;
    if (chunk == 0) {
      const float* r0 = &feat[p2 * PIXSTRIDE];
      const float4 a4 = *reinterpret_cast<const float4*>(r0 + i0);
      const float4 b4 = *reinterpret_cast<const float4*>(r0 + j0);
      f0a[0] = a4.x; f0a[1] = a4.y; f0a[2] = a4.z; f0a[3] = a4.w;
      f0b[0] = b4.x; f0b[1] = b4.y; f0b[2] = b4.z; f0b[3] = b4.w;
      #pragma unroll
      for (int i = 0; i < 4; i++) { pa[i] = f0a[i]; pb[i] = f0b[i]; fsum[i] = f0a[i]; }
      tstart = 1;
    }

    for (int tt = tstart; tt < CHUNK; tt++) {
      const float* row = &feat[p2 * PIXSTRIDE + tt * FROW];
      const float4 a4 = *reinterpret_cast<const float4*>(row + i0);
      const float4 b4 = *reinterpret_cast<const float4*>(row + j0);
      float fa[4] = {a4.x, a4.y, a4.z, a4.w};
      float fb[4] = {b4.x, b4.y, b4.z, b4.w};
      float av[4], bv[4];
      #pragma unroll
      for (int i = 0; i < 4; i++) {
        av[i] = 0.5f * (fa[i] + pa[i]) - f0a[i];
        bv[i] = fb[i] - pb[i];
        fsum[i] += fa[i];
        pa[i] = fa[i]; pb[i] = fb[i];
      }
      #pragma unroll
      for (int i = 0; i < 4; i++)
        #pragma unroll
        for (int j = 0; j < 4; j++) accv[i][j] += av[i] * bv[j];
    }
    __syncthreads();
  }

  // ===== write sig: core tile + analytic tch row/col/corner + lvl1 =====
  {
    const int ph = th4 + (p2 >> 2), pw = tw4 + (p2 & 3);
    float* sb = sig + (size_t)b * KTOT + (size_t)(ph * WW + pw) * SIG;
    #pragma unroll
    for (int ii = 0; ii < 4; ii++)
      #pragma unroll
      for (int jj = 0; jj < 4; jj++)
        sb[NFC + (i0 + ii) * NFC + (j0 + jj)] = accv[ii][jj];
    if (jt == 0) {
      #pragma unroll
      for (int ii = 0; ii < 4; ii++) {
        const int c = i0 + ii;
        const float f0 = f0a[ii], f95 = pa[ii], fs = fsum[ii];
        sb[c] = f95 - f0;                                            // lvl1
        sb[NFC + c * NFC + 16] = (fs - 95.5f * f0 - 0.5f * f95) * (1.f / 95.f);
        sb[NFC + 16 * NFC + c] = (95.5f * f95 + 0.5f * f0 - fs) * (1.f / 95.f);
      }
      if (it == 0) { sb[16] = 1.0f; sb[NFC + 16 * NFC + 16] = 0.5f; }
    }
  }
}

// ---------------------------------------------------------------------------
// Kernel 2: MLP-1 as K-split GEMM. acc(64,32) += sig(64,122400) @ w1(122400,32)
// ---------------------------------------------------------------------------
__global__ __launch_bounds__(256) void mlp1_gemm(
    const float* __restrict__ sig, const float* __restrict__ w1,
    float* __restrict__ acc)
{
  __shared__ __align__(16) float ldsT[KS * 68];   // [k][b], row pad 68
  const int tid = threadIdx.x;
  const int k0 = blockIdx.x * KS;

  #pragma unroll
  for (int r = 0; r < (64 * KS) / 256; r++) {   // 30
    int idx = r * 256 + tid;
    int b = idx / KS, kk = idx % KS;
    ldsT[kk * 68 + b] = sig[(size_t)b * KTOT + k0 + kk];
  }
  __syncthreads();

  const int n = tid & 31, bq = tid >> 5;
  float a8[8];
  #pragma unroll
  for (int i = 0; i < 8; i++) a8[i] = 0.f;
  const float* w1p = w1 + (size_t)k0 * 32 + n;

  #pragma unroll 4
  for (int kk = 0; kk < KS; kk++) {
    const float w = w1p[(size_t)kk * 32];
    const float4 s0 = *reinterpret_cast<const float4*>(&ldsT[kk * 68 + bq * 8]);
    const float4 s1 = *reinterpret_cast<const float4*>(&ldsT[kk * 68 + bq * 8 + 4]);
    a8[0] += s0.x * w; a8[1] += s0.y * w; a8[2] += s0.z * w; a8[3] += s0.w * w;
    a8[4] += s1.x * w; a8[5] += s1.y * w; a8[6] += s1.z * w; a8[7] += s1.w * w;
  }
  #pragma unroll
  for (int i = 0; i < 8; i++)
    atomicAdd(&acc[(bq * 8 + i) * 32 + n], a8[i]);
}

// ---------------------------------------------------------------------------
// Kernel 3: MLP layers 2-4. 8 blocks x 256 thr; 32 lanes per batch element,
// shuffle-broadcast dots (weights read coalesced, no serial 1-block tail).
// ---------------------------------------------------------------------------
__global__ __launch_bounds__(256) void mlp_tail(
    const float* __restrict__ acc, const float* __restrict__ b1,
    const float* __restrict__ w2, const float* __restrict__ b2,
    const float* __restrict__ w3, const float* __restrict__ b3,
    const float* __restrict__ w4, const float* __restrict__ b4,
    float* __restrict__ out)
{
  const int tid = threadIdx.x;
  const int n = tid & 31;
  const int b = blockIdx.x * 8 + (tid >> 5);
  const int lane = tid & 63;
  const int grp = lane & 32;          // 32-lane group base within the wave

  float h = acc[b * 32 + n] + b1[n];
  h = fmaxf(h, 0.f);

  float v = b2[n];
  #pragma unroll
  for (int k = 0; k < 32; k++)
    v += __shfl(h, grp + k, 64) * w2[k * 32 + n];
  h = fmaxf(v, 0.f);

  v = b3[n];
  #pragma unroll
  for (int k = 0; k < 32; k++)
    v += __shfl(h, grp + k, 64) * w3[k * 32 + n];
  h = fmaxf(v, 0.f);

  float p = h * w4[n];
  #pragma unroll
  for (int o = 16; o >= 1; o >>= 1) p += __shfl_xor(p, o, 64);
  if (n == 0) out[b] = p + b4[0];
}

extern "C" void kernel_launch(void* const* d_in, const int* in_sizes, int n_in,
                              void* d_out, int out_size, void* d_ws, size_t ws_size,
                              hipStream_t stream) {
  const float* x  = (const float*)d_in[0];
  const float* cw = (const float*)d_in[1];
  const float* cb = (const float*)d_in[2];
  const float* w1 = (const float*)d_in[3];
  const float* b1 = (const float*)d_in[4];
  const float* w2 = (const float*)d_in[5];
  const float* b2 = (const float*)d_in[6];
  const float* w3 = (const float*)d_in[7];
  const float* b3 = (const float*)d_in[8];
  const float* w4 = (const float*)d_in[9];
  const float* b4 = (const float*)d_in[10];
  float* out = (float*)d_out;

  float* acc  = (float*)d_ws;                    // 8 KB
  float* sigm = (float*)((char*)d_ws + 8192);    // 31.3 MB

  hipMemsetAsync(acc, 0, BB * 32 * sizeof(float), stream);
  sig_kernel<<<dim3(1600), dim3(256), 0, stream>>>(x, cw, cb, sigm);
  mlp1_gemm<<<dim3(NKBLK), dim3(256), 0, stream>>>(sigm, w1, acc);
  mlp_tail<<<dim3(8), dim3(256), 0, stream>>>(acc, b1, w2, b2, w3, b3, w4, b4, out);
}